// Round 10
// baseline (226.426 us; speedup 1.0000x reference)
//
#include <hip/hip_runtime.h>

typedef __bf16 bf16x8 __attribute__((ext_vector_type(8)));
typedef float f32x4 __attribute__((ext_vector_type(4)));

__device__ __forceinline__ unsigned short f2bf(float f) {
  unsigned int u = __builtin_bit_cast(unsigned int, f);
  unsigned int r = (u + 0x7fffu + ((u >> 16) & 1u)) >> 16;
  return (unsigned short)r;
}

__device__ __forceinline__ void load16_lds(const unsigned short* g, unsigned short* l) {
  __builtin_amdgcn_global_load_lds(
      (const __attribute__((address_space(1))) void*)g,
      (__attribute__((address_space(3))) void*)l, 16, 0, 0);
}

// ---------------- fused pre-pass: x cvt + W1/W2 transpose + W3t + zero(out3) ----------------

__global__ __launch_bounds__(256) void prepass(
    const float* __restrict__ x, const float* __restrict__ W1,
    const float* __restrict__ W2, const float* __restrict__ W3,
    unsigned short* __restrict__ xbf, unsigned short* __restrict__ w1t,
    unsigned short* __restrict__ w2t, unsigned short* __restrict__ w3t,
    float* __restrict__ out3) {
  __shared__ float tile[32][33];
  const int bid = blockIdx.x;
  const int t = threadIdx.x;
  if (bid < 2048) {
    for (int i = bid * 256 + t; i < 2097152; i += 2048 * 256) {
      float4 f = ((const float4*)x)[i];
      uint2 o;
      o.x = (unsigned)f2bf(f.x) | ((unsigned)f2bf(f.y) << 16);
      o.y = (unsigned)f2bf(f.z) | ((unsigned)f2bf(f.w) << 16);
      ((uint2*)xbf)[i] = o;
    }
  } else if (bid < 3072) {
    int ti = bid - 2048;
    int n0 = (ti & 31) * 32, k0 = (ti >> 5) * 32;
    int tx = t & 31, ty = t >> 5;
    #pragma unroll
    for (int r = 0; r < 32; r += 8)
      tile[ty + r][tx] = W1[(size_t)(k0 + ty + r) * 1024 + n0 + tx];
    __syncthreads();
    #pragma unroll
    for (int r = 0; r < 32; r += 8)
      w1t[(size_t)(n0 + ty + r) * 1024 + k0 + tx] = f2bf(tile[tx][ty + r]);
  } else if (bid < 5120) {
    int ti = bid - 3072;
    int n0 = (ti & 63) * 32, k0 = (ti >> 6) * 32;
    int tx = t & 31, ty = t >> 5;
    #pragma unroll
    for (int r = 0; r < 32; r += 8)
      tile[ty + r][tx] = W2[(size_t)(k0 + ty + r) * 2048 + n0 + tx];
    __syncthreads();
    #pragma unroll
    for (int r = 0; r < 32; r += 8)
      w2t[(size_t)(n0 + ty + r) * 1024 + k0 + tx] = f2bf(tile[tx][ty + r]);
  } else if (bid < 5632) {
    int idx = (bid - 5120) * 256 + t;
    int n = idx >> 11, k = idx & 2047;
    w3t[idx] = f2bf((n < 50) ? W3[(size_t)k * 50 + n] : 0.f);
  } else {
    // zero out3 [8192][64] fp32 = 131072 float4
    int i = (bid - 5632) * 256 + t;
    ((float4*)out3)[i] = make_float4(0.f, 0.f, 0.f, 0.f);
  }
}

// ---------------- GEMM1 (128x64 n-tile): h1 = relu(xbf @ w1t^T + b1) ----------------

__global__ __launch_bounds__(256) void gemm_bt_relu_n64(
    const unsigned short* __restrict__ A,
    const unsigned short* __restrict__ Bt,
    const float* __restrict__ bias,
    unsigned short* __restrict__ C,
    int N, int K) {
  __shared__ __align__(16) unsigned short smem[128 * 64 + 64 * 64];
  unsigned short* As = smem;
  unsigned short* Bs = smem + 128 * 64;
  const int t = threadIdx.x;
  const int m0 = blockIdx.x * 128;
  const int n0 = blockIdx.y * 64;
  const int lane = t & 63, wv = t >> 6;
  const int l16 = lane & 15, quad = lane >> 4;
  const int wm = (wv >> 1) * 64, wn = (wv & 1) * 32;

  const int srow = t >> 3;
  const int scol = ((t & 7) ^ (srow & 7)) * 8;
  const unsigned short* Ag0 = A + (size_t)(m0 + srow) * K + scol;
  const unsigned short* Bg0 = Bt + (size_t)(n0 + srow) * K + scol;
  unsigned short* AsW = As + wv * 8 * 64;
  unsigned short* BsW = Bs + wv * 8 * 64;

  f32x4 acc[4][2] = {};

  for (int k0 = 0; k0 < K; k0 += 64) {
    #pragma unroll
    for (int r = 0; r < 4; ++r)
      load16_lds(Ag0 + (size_t)(r * 32) * K + k0, AsW + r * 32 * 64);
    #pragma unroll
    for (int r = 0; r < 2; ++r)
      load16_lds(Bg0 + (size_t)(r * 32) * K + k0, BsW + r * 32 * 64);
    __syncthreads();
    #pragma unroll
    for (int half = 0; half < 2; ++half) {
      bf16x8 af[4], bfr[2];
      #pragma unroll
      for (int mi = 0; mi < 4; ++mi) {
        int row = wm + mi * 16 + l16;
        int pb = (half * 4 + quad) ^ (row & 7);
        af[mi] = *(const bf16x8*)&As[row * 64 + pb * 8];
      }
      #pragma unroll
      for (int ni = 0; ni < 2; ++ni) {
        int row = wn + ni * 16 + l16;
        int pb = (half * 4 + quad) ^ (row & 7);
        bfr[ni] = *(const bf16x8*)&Bs[row * 64 + pb * 8];
      }
      #pragma unroll
      for (int mi = 0; mi < 4; ++mi)
        #pragma unroll
        for (int ni = 0; ni < 2; ++ni)
          acc[mi][ni] = __builtin_amdgcn_mfma_f32_16x16x32_bf16(
              af[mi], bfr[ni], acc[mi][ni], 0, 0, 0);
    }
    __syncthreads();
  }

  unsigned short* Cs = smem;
  #pragma unroll
  for (int ni = 0; ni < 2; ++ni) {
    int col = wn + ni * 16 + l16;
    float bv = bias[n0 + col];
    #pragma unroll
    for (int mi = 0; mi < 4; ++mi) {
      #pragma unroll
      for (int r = 0; r < 4; ++r) {
        int row = wm + mi * 16 + quad * 4 + r;
        Cs[row * 64 + col] = f2bf(fmaxf(acc[mi][ni][r] + bv, 0.f));
      }
    }
  }
  __syncthreads();
  #pragma unroll
  for (int j = 0; j < 4; ++j) {
    int idx = j * 256 + t;
    int row = idx >> 3;
    int cc = (idx & 7) * 8;
    *(uint4*)&C[(size_t)(m0 + row) * N + n0 + cc] = *(const uint4*)&Cs[row * 64 + cc];
  }
}

// ---------------- fused GEMM2 + GEMM3-partial (atomic accumulate) ----------------
// Block (m0 = bx*128, n0 = by*128): h2 tile = relu(h1@w2t^T + b2) in LDS, then
// mini-GEMM vs w3t chunk; partials atomicAdd'ed into out3[8192][64].
// The 16 blocks contending per out3 element share an XCD (ids differ by 64).

__global__ __launch_bounds__(256) void gemm2_fused(
    const unsigned short* __restrict__ A,    // h1 [8192,1024]
    const unsigned short* __restrict__ Bt,   // w2t [2048,1024]
    const float* __restrict__ bias,          // b2
    const unsigned short* __restrict__ W3t,  // w3t [64,2048]
    float* __restrict__ out3) {              // [8192][64] fp32, pre-zeroed
  constexpr int K = 1024;
  __shared__ __align__(16) unsigned short smem[2 * 128 * 64];  // 32 KB
  unsigned short* As = smem;
  unsigned short* Bs = smem + 128 * 64;
  const int t = threadIdx.x;
  const int m0 = blockIdx.x * 128;
  const int n0 = blockIdx.y * 128;
  const int lane = t & 63, wv = t >> 6;
  const int l16 = lane & 15, quad = lane >> 4;
  const int wm = (wv >> 1) * 64, wn = (wv & 1) * 64;

  const int srow = t >> 3;
  const int scol = ((t & 7) ^ (srow & 7)) * 8;
  const unsigned short* Ag0 = A + (size_t)(m0 + srow) * K + scol;
  const unsigned short* Bg0 = Bt + (size_t)(n0 + srow) * K + scol;
  unsigned short* AsW = As + wv * 8 * 64;
  unsigned short* BsW = Bs + wv * 8 * 64;

  f32x4 acc[4][4] = {};

  for (int k0 = 0; k0 < K; k0 += 64) {
    #pragma unroll
    for (int r = 0; r < 4; ++r) {
      load16_lds(Ag0 + (size_t)(r * 32) * K + k0, AsW + r * 32 * 64);
      load16_lds(Bg0 + (size_t)(r * 32) * K + k0, BsW + r * 32 * 64);
    }
    __syncthreads();
    #pragma unroll
    for (int half = 0; half < 2; ++half) {
      bf16x8 af[4], bfr[4];
      #pragma unroll
      for (int mi = 0; mi < 4; ++mi) {
        int row = wm + mi * 16 + l16;
        int pb = (half * 4 + quad) ^ (row & 7);
        af[mi] = *(const bf16x8*)&As[row * 64 + pb * 8];
      }
      #pragma unroll
      for (int ni = 0; ni < 4; ++ni) {
        int row = wn + ni * 16 + l16;
        int pb = (half * 4 + quad) ^ (row & 7);
        bfr[ni] = *(const bf16x8*)&Bs[row * 64 + pb * 8];
      }
      #pragma unroll
      for (int mi = 0; mi < 4; ++mi)
        #pragma unroll
        for (int ni = 0; ni < 4; ++ni)
          acc[mi][ni] = __builtin_amdgcn_mfma_f32_16x16x32_bf16(
              af[mi], bfr[ni], acc[mi][ni], 0, 0, 0);
    }
    __syncthreads();
  }

  // epilogue 1: relu'd bf16 h2 tile into LDS, 16-block XOR swizzle
  unsigned short* Cs = smem;  // 128x128 bf16 = 32 KB
  #pragma unroll
  for (int ni = 0; ni < 4; ++ni) {
    int col = wn + ni * 16 + l16;
    float bv = bias[n0 + col];
    int cb = col >> 3, cw = col & 7;
    #pragma unroll
    for (int mi = 0; mi < 4; ++mi) {
      #pragma unroll
      for (int r = 0; r < 4; ++r) {
        int row = wm + mi * 16 + quad * 4 + r;
        int pb = cb ^ (row & 15);
        Cs[row * 128 + pb * 8 + cw] = f2bf(fmaxf(acc[mi][ni][r] + bv, 0.f));
      }
    }
  }
  // epilogue 2: w3t B-frags direct from global (L2-resident, one-time)
  bf16x8 bq[4][4];
  #pragma unroll
  for (int ks = 0; ks < 4; ++ks)
    #pragma unroll
    for (int nt = 0; nt < 4; ++nt)
      bq[ks][nt] = *(const bf16x8*)&W3t[(size_t)(nt * 16 + l16) * 2048 +
                                        n0 + ks * 32 + quad * 8];
  __syncthreads();

  // epilogue 3: mini-GEMM 128x64x128; wave wv handles rows wv*32..+32
  f32x4 acc2[2][4] = {};
  #pragma unroll
  for (int ks = 0; ks < 4; ++ks) {
    bf16x8 af2[2];
    #pragma unroll
    for (int mt = 0; mt < 2; ++mt) {
      int row = wv * 32 + mt * 16 + l16;
      int pb = (ks * 4 + quad) ^ (row & 15);
      af2[mt] = *(const bf16x8*)&Cs[row * 128 + pb * 8];
    }
    #pragma unroll
    for (int mt = 0; mt < 2; ++mt)
      #pragma unroll
      for (int nt = 0; nt < 4; ++nt)
        acc2[mt][nt] = __builtin_amdgcn_mfma_f32_16x16x32_bf16(
            af2[mt], bq[ks][nt], acc2[mt][nt], 0, 0, 0);
  }

  // epilogue 4: device-scope atomic accumulate into out3
  #pragma unroll
  for (int mt = 0; mt < 2; ++mt) {
    #pragma unroll
    for (int nt = 0; nt < 4; ++nt) {
      int col = nt * 16 + l16;
      #pragma unroll
      for (int r = 0; r < 4; ++r) {
        int row = m0 + wv * 32 + mt * 16 + quad * 4 + r;
        atomicAdd(&out3[(size_t)row * 64 + col], acc2[mt][nt][r]);
      }
    }
  }
}

// ---------------- geometry (reads out3 directly) ----------------

__global__ __launch_bounds__(256) void geom_reduce(
    const float* __restrict__ out3, const float* __restrict__ b3,
    float* __restrict__ outp) {
  __shared__ float s_out3[16 * 64];
  __shared__ float fold[16 * 578];
  const int t = threadIdx.x;
  const int bbase = blockIdx.x * 16;

  for (int i = t; i < 16 * 578; i += 256) fold[i] = 0.f;
  for (int i = t; i < 1024; i += 256) {
    int m = i >> 6, n = i & 63;
    float v = out3[(size_t)(bbase + m) * 64 + n];
    s_out3[i] = v + ((n < 50) ? b3[n] : 0.f);
  }
  __syncthreads();

  {
    const int bl = t >> 4;
    const int p = t & 15;
    const int pi = p >> 2, pj = p & 3;
    const float* o = &s_out3[bl * 64];

    float u00 = 128.f * pi       + o[pi * 5 + pj];
    float v00 = 128.f * pj       + o[25 + pi * 5 + pj];
    float u01 = 128.f * pi       + o[pi * 5 + pj + 1];
    float v01 = 128.f * (pj + 1) + o[25 + pi * 5 + pj + 1];
    float u10 = 128.f * (pi + 1) + o[(pi + 1) * 5 + pj];
    float v10 = 128.f * pj       + o[25 + (pi + 1) * 5 + pj];
    float u11 = 128.f * (pi + 1) + o[(pi + 1) * 5 + pj + 1];
    float v11 = 128.f * (pj + 1) + o[25 + (pi + 1) * 5 + pj + 1];

    float sx = u00 - u10 + u11 - u01;
    float sy = v00 - v10 + v11 - v01;
    float dx1 = u10 - u11, dx2 = u01 - u11;
    float dy1 = v10 - v11, dy2 = v01 - v11;
    float rden = 1.f / (dx1 * dy2 - dx2 * dy1);
    float g = (sx * dy2 - dx2 * sy) * rden;
    float h = (dx1 * sy - sx * dy1) * rden;
    float a = u10 - u00 + g * u10;
    float b = u01 - u00 + h * u01;
    float c = u00;
    float d = v10 - v00 + g * v10;
    float e = v01 - v00 + h * v01;
    float f = v00;

    #pragma unroll
    for (int ai = 0; ai < 5; ++ai) {
      #pragma unroll
      for (int bi = 0; bi < 5; ++bi) {
        float s = 0.25f * ai, tt = 0.25f * bi;
        float rw = 1.f / (g * s + h * tt + 1.f);
        float xx = (a * s + b * tt + c) * rw;
        float yy = (d * s + e * tt + f) * rw;
        int gi = pi * 4 + ai, gj = pj * 4 + bi;
        atomicAdd(&fold[(bl * 2 + 0) * 289 + gi * 17 + gj], xx);
        atomicAdd(&fold[(bl * 2 + 1) * 289 + gi * 17 + gj], yy);
      }
    }
  }
  __syncthreads();

  for (int i = t; i < 16 * 578; i += 256) {
    int blb = i / 578;
    int rem = i - blb * 578;
    int ch = rem / 289;
    int ij = rem - ch * 289;
    int gi = ij / 17, gj = ij - gi * 17;
    float val = fold[i];
    if ((gi % 4 == 0) && (gj % 4 == 0)) val *= 0.5f;
    if ((gi == 0 || gi == 16) && (gj == 0 || gj == 16)) val *= 2.f;
    val -= (ch == 0) ? 32.f * gi : 32.f * gj;
    outp[(size_t)(bbase + blb) * 578 + rem] = val;
  }
}

// ---------------- launch ----------------

extern "C" void kernel_launch(void* const* d_in, const int* in_sizes, int n_in,
                              void* d_out, int out_size, void* d_ws, size_t ws_size,
                              hipStream_t stream) {
  const float* x  = (const float*)d_in[0];
  const float* W1 = (const float*)d_in[1];
  const float* b1 = (const float*)d_in[2];
  const float* W2 = (const float*)d_in[3];
  const float* b2 = (const float*)d_in[4];
  const float* W3 = (const float*)d_in[5];
  const float* b3 = (const float*)d_in[6];
  float* outp = (float*)d_out;

  // workspace (~40.3 MB):
  char* ws = (char*)d_ws;
  unsigned short* xbf = (unsigned short*)ws;                                  // 16 MB
  unsigned short* w1t = (unsigned short*)(ws + (size_t)16 * 1024 * 1024);     //  2 MB
  unsigned short* w2t = (unsigned short*)(ws + (size_t)18 * 1024 * 1024);     //  4 MB
  unsigned short* w3t = (unsigned short*)(ws + (size_t)22 * 1024 * 1024);     // .25 MB
  float* out3 = (float*)(ws + (size_t)22 * 1024 * 1024 + 256 * 1024);         //  2 MB
  unsigned short* h1  = (unsigned short*)(ws + (size_t)24 * 1024 * 1024 + 256 * 1024);  // 16 MB

  prepass<<<6144, 256, 0, stream>>>(x, W1, W2, W3, xbf, w1t, w2t, w3t, out3);

  gemm_bt_relu_n64<<<dim3(64, 16), 256, 0, stream>>>(xbf, w1t, b1, h1, 1024, 1024);
  gemm2_fused<<<dim3(64, 16), 256, 0, stream>>>(h1, w2t, b2, w3t, out3);
  geom_reduce<<<512, 256, 0, stream>>>(out3, b3, outp);
}

// Round 11
// 216.881 us; speedup vs baseline: 1.0440x; 1.0440x over previous
//
#include <hip/hip_runtime.h>

typedef __bf16 bf16x8 __attribute__((ext_vector_type(8)));
typedef float f32x4 __attribute__((ext_vector_type(4)));

__device__ __forceinline__ unsigned short f2bf(float f) {
  unsigned int u = __builtin_bit_cast(unsigned int, f);
  unsigned int r = (u + 0x7fffu + ((u >> 16) & 1u)) >> 16;
  return (unsigned short)r;
}

__device__ __forceinline__ void load16_lds(const unsigned short* g, unsigned short* l) {
  __builtin_amdgcn_global_load_lds(
      (const __attribute__((address_space(1))) void*)g,
      (__attribute__((address_space(3))) void*)l, 16, 0, 0);
}

// ---------------- fused pre-pass: x cvt + W1/W2 transpose + W3t ----------------

__global__ __launch_bounds__(256) void prepass(
    const float* __restrict__ x, const float* __restrict__ W1,
    const float* __restrict__ W2, const float* __restrict__ W3,
    unsigned short* __restrict__ xbf, unsigned short* __restrict__ w1t,
    unsigned short* __restrict__ w2t, unsigned short* __restrict__ w3t) {
  __shared__ float tile[32][33];
  const int bid = blockIdx.x;
  const int t = threadIdx.x;
  if (bid < 2048) {
    for (int i = bid * 256 + t; i < 2097152; i += 2048 * 256) {
      float4 f = ((const float4*)x)[i];
      uint2 o;
      o.x = (unsigned)f2bf(f.x) | ((unsigned)f2bf(f.y) << 16);
      o.y = (unsigned)f2bf(f.z) | ((unsigned)f2bf(f.w) << 16);
      ((uint2*)xbf)[i] = o;
    }
  } else if (bid < 3072) {
    int ti = bid - 2048;
    int n0 = (ti & 31) * 32, k0 = (ti >> 5) * 32;
    int tx = t & 31, ty = t >> 5;
    #pragma unroll
    for (int r = 0; r < 32; r += 8)
      tile[ty + r][tx] = W1[(size_t)(k0 + ty + r) * 1024 + n0 + tx];
    __syncthreads();
    #pragma unroll
    for (int r = 0; r < 32; r += 8)
      w1t[(size_t)(n0 + ty + r) * 1024 + k0 + tx] = f2bf(tile[tx][ty + r]);
  } else if (bid < 5120) {
    int ti = bid - 3072;
    int n0 = (ti & 63) * 32, k0 = (ti >> 6) * 32;
    int tx = t & 31, ty = t >> 5;
    #pragma unroll
    for (int r = 0; r < 32; r += 8)
      tile[ty + r][tx] = W2[(size_t)(k0 + ty + r) * 2048 + n0 + tx];
    __syncthreads();
    #pragma unroll
    for (int r = 0; r < 32; r += 8)
      w2t[(size_t)(n0 + ty + r) * 1024 + k0 + tx] = f2bf(tile[tx][ty + r]);
  } else {
    int idx = (bid - 5120) * 256 + t;
    int n = idx >> 11, k = idx & 2047;
    w3t[idx] = f2bf((n < 50) ? W3[(size_t)k * 50 + n] : 0.f);
  }
}

// ---------------- GEMM1 (128x64 n-tile): h1 = relu(xbf @ w1t^T + b1) ----------------

__global__ __launch_bounds__(256) void gemm_bt_relu_n64(
    const unsigned short* __restrict__ A,
    const unsigned short* __restrict__ Bt,
    const float* __restrict__ bias,
    unsigned short* __restrict__ C,
    int N, int K) {
  __shared__ __align__(16) unsigned short smem[128 * 64 + 64 * 64];
  unsigned short* As = smem;
  unsigned short* Bs = smem + 128 * 64;
  const int t = threadIdx.x;
  const int m0 = blockIdx.x * 128;
  const int n0 = blockIdx.y * 64;
  const int lane = t & 63, wv = t >> 6;
  const int l16 = lane & 15, quad = lane >> 4;
  const int wm = (wv >> 1) * 64, wn = (wv & 1) * 32;

  const int srow = t >> 3;
  const int scol = ((t & 7) ^ (srow & 7)) * 8;
  const unsigned short* Ag0 = A + (size_t)(m0 + srow) * K + scol;
  const unsigned short* Bg0 = Bt + (size_t)(n0 + srow) * K + scol;
  unsigned short* AsW = As + wv * 8 * 64;
  unsigned short* BsW = Bs + wv * 8 * 64;

  f32x4 acc[4][2] = {};

  for (int k0 = 0; k0 < K; k0 += 64) {
    #pragma unroll
    for (int r = 0; r < 4; ++r)
      load16_lds(Ag0 + (size_t)(r * 32) * K + k0, AsW + r * 32 * 64);
    #pragma unroll
    for (int r = 0; r < 2; ++r)
      load16_lds(Bg0 + (size_t)(r * 32) * K + k0, BsW + r * 32 * 64);
    __syncthreads();
    #pragma unroll
    for (int half = 0; half < 2; ++half) {
      bf16x8 af[4], bfr[2];
      #pragma unroll
      for (int mi = 0; mi < 4; ++mi) {
        int row = wm + mi * 16 + l16;
        int pb = (half * 4 + quad) ^ (row & 7);
        af[mi] = *(const bf16x8*)&As[row * 64 + pb * 8];
      }
      #pragma unroll
      for (int ni = 0; ni < 2; ++ni) {
        int row = wn + ni * 16 + l16;
        int pb = (half * 4 + quad) ^ (row & 7);
        bfr[ni] = *(const bf16x8*)&Bs[row * 64 + pb * 8];
      }
      #pragma unroll
      for (int mi = 0; mi < 4; ++mi)
        #pragma unroll
        for (int ni = 0; ni < 2; ++ni)
          acc[mi][ni] = __builtin_amdgcn_mfma_f32_16x16x32_bf16(
              af[mi], bfr[ni], acc[mi][ni], 0, 0, 0);
    }
    __syncthreads();
  }

  unsigned short* Cs = smem;
  #pragma unroll
  for (int ni = 0; ni < 2; ++ni) {
    int col = wn + ni * 16 + l16;
    float bv = bias[n0 + col];
    #pragma unroll
    for (int mi = 0; mi < 4; ++mi) {
      #pragma unroll
      for (int r = 0; r < 4; ++r) {
        int row = wm + mi * 16 + quad * 4 + r;
        Cs[row * 64 + col] = f2bf(fmaxf(acc[mi][ni][r] + bv, 0.f));
      }
    }
  }
  __syncthreads();
  #pragma unroll
  for (int j = 0; j < 4; ++j) {
    int idx = j * 256 + t;
    int row = idx >> 3;
    int cc = (idx & 7) * 8;
    *(uint4*)&C[(size_t)(m0 + row) * N + n0 + cc] = *(const uint4*)&Cs[row * 64 + cc];
  }
}

// ---------------- fused GEMM2 + GEMM3-partial ----------------
// Block (m0 = bx*128, n0 = by*128): h2 tile = relu(h1@w2t^T + b2) in LDS, then
// mini-GEMM vs w3t chunk -> plain fp32 partial stores (no atomics — r10 showed
// device atomics stream to the coherence point, same HBM bytes + RMW latency).
// w3t B-fragments are K-loop-invariant -> prefetched BEFORE the K-loop so their
// global latency overlaps the first K-iterations.

__global__ __launch_bounds__(256) void gemm2_fused(
    const unsigned short* __restrict__ A,    // h1 [8192,1024]
    const unsigned short* __restrict__ Bt,   // w2t [2048,1024]
    const float* __restrict__ bias,          // b2
    const unsigned short* __restrict__ W3t,  // w3t [64,2048]
    float* __restrict__ part) {              // [16][8192][64]
  constexpr int K = 1024;
  __shared__ __align__(16) unsigned short smem[2 * 128 * 64];  // 32 KB
  unsigned short* As = smem;
  unsigned short* Bs = smem + 128 * 64;
  const int t = threadIdx.x;
  const int m0 = blockIdx.x * 128;
  const int n0 = blockIdx.y * 128;
  const int lane = t & 63, wv = t >> 6;
  const int l16 = lane & 15, quad = lane >> 4;
  const int wm = (wv >> 1) * 64, wn = (wv & 1) * 64;

  const int srow = t >> 3;
  const int scol = ((t & 7) ^ (srow & 7)) * 8;
  const unsigned short* Ag0 = A + (size_t)(m0 + srow) * K + scol;
  const unsigned short* Bg0 = Bt + (size_t)(n0 + srow) * K + scol;
  unsigned short* AsW = As + wv * 8 * 64;
  unsigned short* BsW = Bs + wv * 8 * 64;

  // prefetch K-loop-invariant w3t fragments + bias (latency hidden by K-loop)
  bf16x8 bq[4][4];
  #pragma unroll
  for (int ks = 0; ks < 4; ++ks)
    #pragma unroll
    for (int nt = 0; nt < 4; ++nt)
      bq[ks][nt] = *(const bf16x8*)&W3t[(size_t)(nt * 16 + l16) * 2048 +
                                        n0 + ks * 32 + quad * 8];
  float bv4[4];
  #pragma unroll
  for (int ni = 0; ni < 4; ++ni) bv4[ni] = bias[n0 + wn + ni * 16 + l16];

  f32x4 acc[4][4] = {};

  for (int k0 = 0; k0 < K; k0 += 64) {
    #pragma unroll
    for (int r = 0; r < 4; ++r) {
      load16_lds(Ag0 + (size_t)(r * 32) * K + k0, AsW + r * 32 * 64);
      load16_lds(Bg0 + (size_t)(r * 32) * K + k0, BsW + r * 32 * 64);
    }
    __syncthreads();
    #pragma unroll
    for (int half = 0; half < 2; ++half) {
      bf16x8 af[4], bfr[4];
      #pragma unroll
      for (int mi = 0; mi < 4; ++mi) {
        int row = wm + mi * 16 + l16;
        int pb = (half * 4 + quad) ^ (row & 7);
        af[mi] = *(const bf16x8*)&As[row * 64 + pb * 8];
      }
      #pragma unroll
      for (int ni = 0; ni < 4; ++ni) {
        int row = wn + ni * 16 + l16;
        int pb = (half * 4 + quad) ^ (row & 7);
        bfr[ni] = *(const bf16x8*)&Bs[row * 64 + pb * 8];
      }
      #pragma unroll
      for (int mi = 0; mi < 4; ++mi)
        #pragma unroll
        for (int ni = 0; ni < 4; ++ni)
          acc[mi][ni] = __builtin_amdgcn_mfma_f32_16x16x32_bf16(
              af[mi], bfr[ni], acc[mi][ni], 0, 0, 0);
    }
    __syncthreads();
  }

  // epilogue 1: relu'd bf16 h2 tile into LDS, 16-block XOR swizzle
  unsigned short* Cs = smem;  // 128x128 bf16 = 32 KB
  #pragma unroll
  for (int ni = 0; ni < 4; ++ni) {
    int col = wn + ni * 16 + l16;
    float bv = bv4[ni];
    int cb = col >> 3, cw = col & 7;
    #pragma unroll
    for (int mi = 0; mi < 4; ++mi) {
      #pragma unroll
      for (int r = 0; r < 4; ++r) {
        int row = wm + mi * 16 + quad * 4 + r;
        int pb = cb ^ (row & 15);
        Cs[row * 128 + pb * 8 + cw] = f2bf(fmaxf(acc[mi][ni][r] + bv, 0.f));
      }
    }
  }
  __syncthreads();

  // epilogue 2: mini-GEMM 128x64x128; wave wv handles rows wv*32..+32
  f32x4 acc2[2][4] = {};
  #pragma unroll
  for (int ks = 0; ks < 4; ++ks) {
    bf16x8 af2[2];
    #pragma unroll
    for (int mt = 0; mt < 2; ++mt) {
      int row = wv * 32 + mt * 16 + l16;
      int pb = (ks * 4 + quad) ^ (row & 15);
      af2[mt] = *(const bf16x8*)&Cs[row * 128 + pb * 8];
    }
    #pragma unroll
    for (int mt = 0; mt < 2; ++mt)
      #pragma unroll
      for (int nt = 0; nt < 4; ++nt)
        acc2[mt][nt] = __builtin_amdgcn_mfma_f32_16x16x32_bf16(
            af2[mt], bq[ks][nt], acc2[mt][nt], 0, 0, 0);
  }

  // epilogue 3: plain fp32 partial stores
  float* pb3 = part + (size_t)blockIdx.y * 8192 * 64;
  #pragma unroll
  for (int mt = 0; mt < 2; ++mt) {
    #pragma unroll
    for (int nt = 0; nt < 4; ++nt) {
      int col = nt * 16 + l16;
      #pragma unroll
      for (int r = 0; r < 4; ++r) {
        int row = m0 + wv * 32 + mt * 16 + quad * 4 + r;
        pb3[(size_t)row * 64 + col] = acc2[mt][nt][r];
      }
    }
  }
}

// ---------------- geometry + 16-way partial reduction ----------------

__global__ __launch_bounds__(256) void geom_reduce(
    const float* __restrict__ part, const float* __restrict__ b3,
    float* __restrict__ outp) {
  __shared__ float s_out3[16 * 64];
  __shared__ float fold[16 * 578];
  const int t = threadIdx.x;
  const int bbase = blockIdx.x * 16;

  for (int i = t; i < 16 * 578; i += 256) fold[i] = 0.f;
  for (int i = t; i < 1024; i += 256) {
    int m = i >> 6, n = i & 63;
    size_t idx = (size_t)(bbase + m) * 64 + n;
    float v = 0.f;
    #pragma unroll
    for (int z = 0; z < 16; ++z) v += part[idx + (size_t)z * 8192 * 64];
    s_out3[i] = v + ((n < 50) ? b3[n] : 0.f);
  }
  __syncthreads();

  {
    const int bl = t >> 4;
    const int p = t & 15;
    const int pi = p >> 2, pj = p & 3;
    const float* o = &s_out3[bl * 64];

    float u00 = 128.f * pi       + o[pi * 5 + pj];
    float v00 = 128.f * pj       + o[25 + pi * 5 + pj];
    float u01 = 128.f * pi       + o[pi * 5 + pj + 1];
    float v01 = 128.f * (pj + 1) + o[25 + pi * 5 + pj + 1];
    float u10 = 128.f * (pi + 1) + o[(pi + 1) * 5 + pj];
    float v10 = 128.f * pj       + o[25 + (pi + 1) * 5 + pj];
    float u11 = 128.f * (pi + 1) + o[(pi + 1) * 5 + pj + 1];
    float v11 = 128.f * (pj + 1) + o[25 + (pi + 1) * 5 + pj + 1];

    float sx = u00 - u10 + u11 - u01;
    float sy = v00 - v10 + v11 - v01;
    float dx1 = u10 - u11, dx2 = u01 - u11;
    float dy1 = v10 - v11, dy2 = v01 - v11;
    float rden = 1.f / (dx1 * dy2 - dx2 * dy1);
    float g = (sx * dy2 - dx2 * sy) * rden;
    float h = (dx1 * sy - sx * dy1) * rden;
    float a = u10 - u00 + g * u10;
    float b = u01 - u00 + h * u01;
    float c = u00;
    float d = v10 - v00 + g * v10;
    float e = v01 - v00 + h * v01;
    float f = v00;

    #pragma unroll
    for (int ai = 0; ai < 5; ++ai) {
      #pragma unroll
      for (int bi = 0; bi < 5; ++bi) {
        float s = 0.25f * ai, tt = 0.25f * bi;
        float rw = 1.f / (g * s + h * tt + 1.f);
        float xx = (a * s + b * tt + c) * rw;
        float yy = (d * s + e * tt + f) * rw;
        int gi = pi * 4 + ai, gj = pj * 4 + bi;
        atomicAdd(&fold[(bl * 2 + 0) * 289 + gi * 17 + gj], xx);
        atomicAdd(&fold[(bl * 2 + 1) * 289 + gi * 17 + gj], yy);
      }
    }
  }
  __syncthreads();

  for (int i = t; i < 16 * 578; i += 256) {
    int blb = i / 578;
    int rem = i - blb * 578;
    int ch = rem / 289;
    int ij = rem - ch * 289;
    int gi = ij / 17, gj = ij - gi * 17;
    float val = fold[i];
    if ((gi % 4 == 0) && (gj % 4 == 0)) val *= 0.5f;
    if ((gi == 0 || gi == 16) && (gj == 0 || gj == 16)) val *= 2.f;
    val -= (ch == 0) ? 32.f * gi : 32.f * gj;
    outp[(size_t)(bbase + blb) * 578 + rem] = val;
  }
}

// ---------------- launch ----------------

extern "C" void kernel_launch(void* const* d_in, const int* in_sizes, int n_in,
                              void* d_out, int out_size, void* d_ws, size_t ws_size,
                              hipStream_t stream) {
  const float* x  = (const float*)d_in[0];
  const float* W1 = (const float*)d_in[1];
  const float* b1 = (const float*)d_in[2];
  const float* W2 = (const float*)d_in[3];
  const float* b2 = (const float*)d_in[4];
  const float* W3 = (const float*)d_in[5];
  const float* b3 = (const float*)d_in[6];
  float* outp = (float*)d_out;

  // workspace (~54.5 MB), lifetime aliasing:
  //   [0,33.6M)     part[16][8192][64] fp32 — aliases xbf[0,16M)+w1t[16M,18M),
  //                 both dead before gemm2_fused writes part
  //   [34M,38M)     w2t
  //   [38M,38.25M)  w3t
  //   [38.5M,54.5M) h1
  char* ws = (char*)d_ws;
  unsigned short* xbf = (unsigned short*)ws;
  unsigned short* w1t = (unsigned short*)(ws + (size_t)16 * 1024 * 1024);
  float* part = (float*)ws;
  unsigned short* w2t = (unsigned short*)(ws + (size_t)34 * 1024 * 1024);
  unsigned short* w3t = (unsigned short*)(ws + (size_t)38 * 1024 * 1024);
  unsigned short* h1  = (unsigned short*)(ws + (size_t)38 * 1024 * 1024 + 512 * 1024);

  prepass<<<5632, 256, 0, stream>>>(x, W1, W2, W3, xbf, w1t, w2t, w3t);

  gemm_bt_relu_n64<<<dim3(64, 16), 256, 0, stream>>>(xbf, w1t, b1, h1, 1024, 1024);
  gemm2_fused<<<dim3(64, 16), 256, 0, stream>>>(h1, w2t, b2, w3t, part);
  geom_reduce<<<512, 256, 0, stream>>>(part, b3, outp);
}

// Round 12
// 206.356 us; speedup vs baseline: 1.0973x; 1.0510x over previous
//
#include <hip/hip_runtime.h>

typedef __bf16 bf16x8 __attribute__((ext_vector_type(8)));
typedef float f32x4 __attribute__((ext_vector_type(4)));

__device__ __forceinline__ unsigned short f2bf(float f) {
  unsigned int u = __builtin_bit_cast(unsigned int, f);
  unsigned int r = (u + 0x7fffu + ((u >> 16) & 1u)) >> 16;
  return (unsigned short)r;
}

__device__ __forceinline__ float bf2f(unsigned short u) {
  unsigned int v = ((unsigned int)u) << 16;
  return __builtin_bit_cast(float, v);
}

__device__ __forceinline__ void load16_lds(const unsigned short* g, unsigned short* l) {
  __builtin_amdgcn_global_load_lds(
      (const __attribute__((address_space(1))) void*)g,
      (__attribute__((address_space(3))) void*)l, 16, 0, 0);
}

// ---------------- fused pre-pass: x cvt + W1/W2 transpose + W3t ----------------

__global__ __launch_bounds__(256) void prepass(
    const float* __restrict__ x, const float* __restrict__ W1,
    const float* __restrict__ W2, const float* __restrict__ W3,
    unsigned short* __restrict__ xbf, unsigned short* __restrict__ w1t,
    unsigned short* __restrict__ w2t, unsigned short* __restrict__ w3t) {
  __shared__ float tile[32][33];
  const int bid = blockIdx.x;
  const int t = threadIdx.x;
  if (bid < 2048) {
    for (int i = bid * 256 + t; i < 2097152; i += 2048 * 256) {
      float4 f = ((const float4*)x)[i];
      uint2 o;
      o.x = (unsigned)f2bf(f.x) | ((unsigned)f2bf(f.y) << 16);
      o.y = (unsigned)f2bf(f.z) | ((unsigned)f2bf(f.w) << 16);
      ((uint2*)xbf)[i] = o;
    }
  } else if (bid < 3072) {
    int ti = bid - 2048;
    int n0 = (ti & 31) * 32, k0 = (ti >> 5) * 32;
    int tx = t & 31, ty = t >> 5;
    #pragma unroll
    for (int r = 0; r < 32; r += 8)
      tile[ty + r][tx] = W1[(size_t)(k0 + ty + r) * 1024 + n0 + tx];
    __syncthreads();
    #pragma unroll
    for (int r = 0; r < 32; r += 8)
      w1t[(size_t)(n0 + ty + r) * 1024 + k0 + tx] = f2bf(tile[tx][ty + r]);
  } else if (bid < 5120) {
    int ti = bid - 3072;
    int n0 = (ti & 63) * 32, k0 = (ti >> 6) * 32;
    int tx = t & 31, ty = t >> 5;
    #pragma unroll
    for (int r = 0; r < 32; r += 8)
      tile[ty + r][tx] = W2[(size_t)(k0 + ty + r) * 2048 + n0 + tx];
    __syncthreads();
    #pragma unroll
    for (int r = 0; r < 32; r += 8)
      w2t[(size_t)(n0 + ty + r) * 1024 + k0 + tx] = f2bf(tile[tx][ty + r]);
  } else {
    int idx = (bid - 5120) * 256 + t;
    int n = idx >> 11, k = idx & 2047;
    w3t[idx] = f2bf((n < 50) ? W3[(size_t)k * 50 + n] : 0.f);
  }
}

// ---------------- GEMM1 (128x128): h1 = relu(xbf @ w1t^T + b1) ----------------
// Same per-block structure as gemm2 (8 staging loads : 32 MFMA per BK=64 iter).
// Grid (64 m, 8 n) = 512 blocks.

__global__ __launch_bounds__(256) void gemm1_f128(
    const unsigned short* __restrict__ A,
    const unsigned short* __restrict__ Bt,
    const float* __restrict__ bias,
    unsigned short* __restrict__ C) {
  constexpr int K = 1024, N = 1024;
  __shared__ __align__(16) unsigned short smem[2 * 128 * 64];  // 32 KB
  unsigned short* As = smem;
  unsigned short* Bs = smem + 128 * 64;
  const int t = threadIdx.x;
  const int m0 = blockIdx.x * 128;
  const int n0 = blockIdx.y * 128;
  const int lane = t & 63, wv = t >> 6;
  const int l16 = lane & 15, quad = lane >> 4;
  const int wm = (wv >> 1) * 64, wn = (wv & 1) * 64;

  const int srow = t >> 3;
  const int scol = ((t & 7) ^ (srow & 7)) * 8;
  const unsigned short* Ag0 = A + (size_t)(m0 + srow) * K + scol;
  const unsigned short* Bg0 = Bt + (size_t)(n0 + srow) * K + scol;
  unsigned short* AsW = As + wv * 8 * 64;
  unsigned short* BsW = Bs + wv * 8 * 64;

  f32x4 acc[4][4] = {};

  for (int k0 = 0; k0 < K; k0 += 64) {
    #pragma unroll
    for (int r = 0; r < 4; ++r) {
      load16_lds(Ag0 + (size_t)(r * 32) * K + k0, AsW + r * 32 * 64);
      load16_lds(Bg0 + (size_t)(r * 32) * K + k0, BsW + r * 32 * 64);
    }
    __syncthreads();
    #pragma unroll
    for (int half = 0; half < 2; ++half) {
      bf16x8 af[4], bfr[4];
      #pragma unroll
      for (int mi = 0; mi < 4; ++mi) {
        int row = wm + mi * 16 + l16;
        int pb = (half * 4 + quad) ^ (row & 7);
        af[mi] = *(const bf16x8*)&As[row * 64 + pb * 8];
      }
      #pragma unroll
      for (int ni = 0; ni < 4; ++ni) {
        int row = wn + ni * 16 + l16;
        int pb = (half * 4 + quad) ^ (row & 7);
        bfr[ni] = *(const bf16x8*)&Bs[row * 64 + pb * 8];
      }
      #pragma unroll
      for (int mi = 0; mi < 4; ++mi)
        #pragma unroll
        for (int ni = 0; ni < 4; ++ni)
          acc[mi][ni] = __builtin_amdgcn_mfma_f32_16x16x32_bf16(
              af[mi], bfr[ni], acc[mi][ni], 0, 0, 0);
    }
    __syncthreads();
  }

  unsigned short* Cs = smem;
  #pragma unroll
  for (int ni = 0; ni < 4; ++ni) {
    int col = wn + ni * 16 + l16;
    float bv = bias[n0 + col];
    #pragma unroll
    for (int mi = 0; mi < 4; ++mi) {
      #pragma unroll
      for (int r = 0; r < 4; ++r) {
        int row = wm + mi * 16 + quad * 4 + r;
        Cs[row * 128 + col] = f2bf(fmaxf(acc[mi][ni][r] + bv, 0.f));
      }
    }
  }
  __syncthreads();
  #pragma unroll
  for (int j = 0; j < 8; ++j) {
    int idx = j * 256 + t;
    int row = idx >> 4;
    int cc = (idx & 15) * 8;
    *(uint4*)&C[(size_t)(m0 + row) * N + n0 + cc] = *(const uint4*)&Cs[row * 128 + cc];
  }
}

// ---------------- fused GEMM2 + GEMM3-partial (bf16 partials) ----------------

__global__ __launch_bounds__(256) void gemm2_fused(
    const unsigned short* __restrict__ A,    // h1 [8192,1024]
    const unsigned short* __restrict__ Bt,   // w2t [2048,1024]
    const float* __restrict__ bias,          // b2
    const unsigned short* __restrict__ W3t,  // w3t [64,2048]
    unsigned short* __restrict__ part) {     // [16][8192][64] bf16
  constexpr int K = 1024;
  __shared__ __align__(16) unsigned short smem[2 * 128 * 64];  // 32 KB
  unsigned short* As = smem;
  unsigned short* Bs = smem + 128 * 64;
  const int t = threadIdx.x;
  const int m0 = blockIdx.x * 128;
  const int n0 = blockIdx.y * 128;
  const int lane = t & 63, wv = t >> 6;
  const int l16 = lane & 15, quad = lane >> 4;
  const int wm = (wv >> 1) * 64, wn = (wv & 1) * 64;

  const int srow = t >> 3;
  const int scol = ((t & 7) ^ (srow & 7)) * 8;
  const unsigned short* Ag0 = A + (size_t)(m0 + srow) * K + scol;
  const unsigned short* Bg0 = Bt + (size_t)(n0 + srow) * K + scol;
  unsigned short* AsW = As + wv * 8 * 64;
  unsigned short* BsW = Bs + wv * 8 * 64;

  // prefetch K-loop-invariant w3t fragments + bias (latency hidden by K-loop)
  bf16x8 bq[4][4];
  #pragma unroll
  for (int ks = 0; ks < 4; ++ks)
    #pragma unroll
    for (int nt = 0; nt < 4; ++nt)
      bq[ks][nt] = *(const bf16x8*)&W3t[(size_t)(nt * 16 + l16) * 2048 +
                                        n0 + ks * 32 + quad * 8];
  float bv4[4];
  #pragma unroll
  for (int ni = 0; ni < 4; ++ni) bv4[ni] = bias[n0 + wn + ni * 16 + l16];

  f32x4 acc[4][4] = {};

  for (int k0 = 0; k0 < K; k0 += 64) {
    #pragma unroll
    for (int r = 0; r < 4; ++r) {
      load16_lds(Ag0 + (size_t)(r * 32) * K + k0, AsW + r * 32 * 64);
      load16_lds(Bg0 + (size_t)(r * 32) * K + k0, BsW + r * 32 * 64);
    }
    __syncthreads();
    #pragma unroll
    for (int half = 0; half < 2; ++half) {
      bf16x8 af[4], bfr[4];
      #pragma unroll
      for (int mi = 0; mi < 4; ++mi) {
        int row = wm + mi * 16 + l16;
        int pb = (half * 4 + quad) ^ (row & 7);
        af[mi] = *(const bf16x8*)&As[row * 64 + pb * 8];
      }
      #pragma unroll
      for (int ni = 0; ni < 4; ++ni) {
        int row = wn + ni * 16 + l16;
        int pb = (half * 4 + quad) ^ (row & 7);
        bfr[ni] = *(const bf16x8*)&Bs[row * 64 + pb * 8];
      }
      #pragma unroll
      for (int mi = 0; mi < 4; ++mi)
        #pragma unroll
        for (int ni = 0; ni < 4; ++ni)
          acc[mi][ni] = __builtin_amdgcn_mfma_f32_16x16x32_bf16(
              af[mi], bfr[ni], acc[mi][ni], 0, 0, 0);
    }
    __syncthreads();
  }

  // epilogue 1: relu'd bf16 h2 tile into LDS, 16-block XOR swizzle
  unsigned short* Cs = smem;  // 128x128 bf16 = 32 KB
  #pragma unroll
  for (int ni = 0; ni < 4; ++ni) {
    int col = wn + ni * 16 + l16;
    float bv = bv4[ni];
    int cb = col >> 3, cw = col & 7;
    #pragma unroll
    for (int mi = 0; mi < 4; ++mi) {
      #pragma unroll
      for (int r = 0; r < 4; ++r) {
        int row = wm + mi * 16 + quad * 4 + r;
        int pb = cb ^ (row & 15);
        Cs[row * 128 + pb * 8 + cw] = f2bf(fmaxf(acc[mi][ni][r] + bv, 0.f));
      }
    }
  }
  __syncthreads();

  // epilogue 2: mini-GEMM 128x64x128; wave wv handles rows wv*32..+32
  f32x4 acc2[2][4] = {};
  #pragma unroll
  for (int ks = 0; ks < 4; ++ks) {
    bf16x8 af2[2];
    #pragma unroll
    for (int mt = 0; mt < 2; ++mt) {
      int row = wv * 32 + mt * 16 + l16;
      int pb = (ks * 4 + quad) ^ (row & 15);
      af2[mt] = *(const bf16x8*)&Cs[row * 128 + pb * 8];
    }
    #pragma unroll
    for (int mt = 0; mt < 2; ++mt)
      #pragma unroll
      for (int nt = 0; nt < 4; ++nt)
        acc2[mt][nt] = __builtin_amdgcn_mfma_f32_16x16x32_bf16(
            af2[mt], bq[ks][nt], acc2[mt][nt], 0, 0, 0);
  }

  // epilogue 3: bf16 partial stores (half the write bytes of fp32)
  unsigned short* pb3 = part + (size_t)blockIdx.y * 8192 * 64;
  #pragma unroll
  for (int mt = 0; mt < 2; ++mt) {
    #pragma unroll
    for (int nt = 0; nt < 4; ++nt) {
      int col = nt * 16 + l16;
      #pragma unroll
      for (int r = 0; r < 4; ++r) {
        int row = m0 + wv * 32 + mt * 16 + quad * 4 + r;
        pb3[(size_t)row * 64 + col] = f2bf(acc2[mt][nt][r]);
      }
    }
  }
}

// ---------------- geometry + 16-way bf16 partial reduction ----------------

__global__ __launch_bounds__(256) void geom_reduce(
    const unsigned short* __restrict__ part, const float* __restrict__ b3,
    float* __restrict__ outp) {
  __shared__ float s_out3[16 * 64];
  __shared__ float fold[16 * 578];
  const int t = threadIdx.x;
  const int bbase = blockIdx.x * 16;

  for (int i = t; i < 16 * 578; i += 256) fold[i] = 0.f;
  for (int i = t; i < 1024; i += 256) {
    int m = i >> 6, n = i & 63;
    size_t idx = (size_t)(bbase + m) * 64 + n;
    float v = 0.f;
    #pragma unroll
    for (int z = 0; z < 16; ++z) v += bf2f(part[idx + (size_t)z * 8192 * 64]);
    s_out3[i] = v + ((n < 50) ? b3[n] : 0.f);
  }
  __syncthreads();

  {
    const int bl = t >> 4;
    const int p = t & 15;
    const int pi = p >> 2, pj = p & 3;
    const float* o = &s_out3[bl * 64];

    float u00 = 128.f * pi       + o[pi * 5 + pj];
    float v00 = 128.f * pj       + o[25 + pi * 5 + pj];
    float u01 = 128.f * pi       + o[pi * 5 + pj + 1];
    float v01 = 128.f * (pj + 1) + o[25 + pi * 5 + pj + 1];
    float u10 = 128.f * (pi + 1) + o[(pi + 1) * 5 + pj];
    float v10 = 128.f * pj       + o[25 + (pi + 1) * 5 + pj];
    float u11 = 128.f * (pi + 1) + o[(pi + 1) * 5 + pj + 1];
    float v11 = 128.f * (pj + 1) + o[25 + (pi + 1) * 5 + pj + 1];

    float sx = u00 - u10 + u11 - u01;
    float sy = v00 - v10 + v11 - v01;
    float dx1 = u10 - u11, dx2 = u01 - u11;
    float dy1 = v10 - v11, dy2 = v01 - v11;
    float rden = 1.f / (dx1 * dy2 - dx2 * dy1);
    float g = (sx * dy2 - dx2 * sy) * rden;
    float h = (dx1 * sy - sx * dy1) * rden;
    float a = u10 - u00 + g * u10;
    float b = u01 - u00 + h * u01;
    float c = u00;
    float d = v10 - v00 + g * v10;
    float e = v01 - v00 + h * v01;
    float f = v00;

    #pragma unroll
    for (int ai = 0; ai < 5; ++ai) {
      #pragma unroll
      for (int bi = 0; bi < 5; ++bi) {
        float s = 0.25f * ai, tt = 0.25f * bi;
        float rw = 1.f / (g * s + h * tt + 1.f);
        float xx = (a * s + b * tt + c) * rw;
        float yy = (d * s + e * tt + f) * rw;
        int gi = pi * 4 + ai, gj = pj * 4 + bi;
        atomicAdd(&fold[(bl * 2 + 0) * 289 + gi * 17 + gj], xx);
        atomicAdd(&fold[(bl * 2 + 1) * 289 + gi * 17 + gj], yy);
      }
    }
  }
  __syncthreads();

  for (int i = t; i < 16 * 578; i += 256) {
    int blb = i / 578;
    int rem = i - blb * 578;
    int ch = rem / 289;
    int ij = rem - ch * 289;
    int gi = ij / 17, gj = ij - gi * 17;
    float val = fold[i];
    if ((gi % 4 == 0) && (gj % 4 == 0)) val *= 0.5f;
    if ((gi == 0 || gi == 16) && (gj == 0 || gj == 16)) val *= 2.f;
    val -= (ch == 0) ? 32.f * gi : 32.f * gj;
    outp[(size_t)(bbase + blb) * 578 + rem] = val;
  }
}

// ---------------- launch ----------------

extern "C" void kernel_launch(void* const* d_in, const int* in_sizes, int n_in,
                              void* d_out, int out_size, void* d_ws, size_t ws_size,
                              hipStream_t stream) {
  const float* x  = (const float*)d_in[0];
  const float* W1 = (const float*)d_in[1];
  const float* b1 = (const float*)d_in[2];
  const float* W2 = (const float*)d_in[3];
  const float* b2 = (const float*)d_in[4];
  const float* W3 = (const float*)d_in[5];
  const float* b3 = (const float*)d_in[6];
  float* outp = (float*)d_out;

  // workspace (~54.5 MB), lifetime aliasing:
  //   [0,16.78M)    part[16][8192][64] bf16 — aliases xbf[0,16M)+w1t head,
  //                 both dead before gemm2_fused writes part
  //   [34M,38M)     w2t
  //   [38M,38.25M)  w3t
  //   [38.5M,54.5M) h1
  char* ws = (char*)d_ws;
  unsigned short* xbf = (unsigned short*)ws;
  unsigned short* w1t = (unsigned short*)(ws + (size_t)16 * 1024 * 1024);
  unsigned short* part = (unsigned short*)ws;
  unsigned short* w2t = (unsigned short*)(ws + (size_t)34 * 1024 * 1024);
  unsigned short* w3t = (unsigned short*)(ws + (size_t)38 * 1024 * 1024);
  unsigned short* h1  = (unsigned short*)(ws + (size_t)38 * 1024 * 1024 + 512 * 1024);

  prepass<<<5632, 256, 0, stream>>>(x, W1, W2, W3, xbf, w1t, w2t, w3t);

  gemm1_f128<<<dim3(64, 8), 256, 0, stream>>>(xbf, w1t, b1, h1);
  gemm2_fused<<<dim3(64, 16), 256, 0, stream>>>(h1, w2t, b2, w3t, part);
  geom_reduce<<<512, 256, 0, stream>>>(part, b3, outp);
}